// Round 5
// baseline (103.417 us; speedup 1.0000x reference)
//
#include <hip/hip_runtime.h>

// GCLSTM (K=1 Cheb, H0=C0=0) fused kernel for MI355X — v5.
// Math: i=sig(x@Wi+bi'), t=tanh(x@Wc+bc'), C=i*t, o=sig(x@Wo+bo'+wco*C),
//       out = (o*tanh(C)) @ fcW + fcb.  edge_index/batch/Wg_*/W_f unused.
// v5 = v4 (zero-shuffle permuted-h dataflow) + per-WG LDS staging of the
//     shared constants. v4 was latency-bound: ~80 serialized L2 loads/tile
//     (wave residency 7.8us vs 1.4us compute). Now wfrag(48KB)+bias(2.3KB)
//     live in LDS (staged once per 512-thread WG), fcfrag(16KB) stays
//     global (L1-resident, shared by all waves on the CU).

typedef __attribute__((ext_vector_type(8))) short short8;
typedef __attribute__((ext_vector_type(4))) float f32x4;
typedef __attribute__((ext_vector_type(4))) unsigned uint4_t;

#define N_ROWS 200000
#define IN_DIM 64
#define HID 128
#define OUT_DIM 64

// ws layout (bytes)
#define WFRAG_ELEMS (24 * 2 * 64 * 8)   // 24576 bf16 = 49152 B
#define FCFRAG_OFF  49152               // WFRAG_ELEMS*2
#define FCFRAG_ELEMS (4 * 4 * 64 * 8)   // 8192 bf16 = 16384 B
#define BIAS_OFF    65536               // floats: bi[128],bc[128],bo[128],wco[128] (h-permuted), fcb[64]
#define BIAS_FLOATS 576                 // 4*HID + OUT_DIM

__device__ __forceinline__ short f2bf(float f) {
  unsigned u = __float_as_uint(f);
  u += 0x7FFFu + ((u >> 16) & 1u);   // RNE
  return (short)(u >> 16);
}
__device__ __forceinline__ float fexp2(float z) { return __builtin_amdgcn_exp2f(z); }
__device__ __forceinline__ float frcp(float z)  { return __builtin_amdgcn_rcpf(z); }
__device__ __forceinline__ float fsigmoid(float z) {
  return frcp(1.0f + fexp2(-1.44269504f * z));
}
__device__ __forceinline__ float ftanh(float z) {
  return 1.0f - 2.0f * frcp(1.0f + fexp2(2.88539008f * z));
}
// permuted global hid for GEMM1 tile g (0..7), D-row d (0..15)
__device__ __forceinline__ int hperm(int g, int d) {
  return 32 * (g >> 1) + 2 * (g & 1) + 8 * (d >> 2) + 4 * ((d >> 1) & 1) + (d & 1);
}

// ---- repack: weights -> bf16 MFMA A-fragments, biases -> combined fp32 ----
__global__ void repack_kernel(const float* __restrict__ W_i, const float* __restrict__ W_c,
                              const float* __restrict__ W_o, const float* __restrict__ fc_W,
                              const float* __restrict__ bg_i, const float* __restrict__ bg_c,
                              const float* __restrict__ bg_o,
                              const float* __restrict__ b_i, const float* __restrict__ b_c,
                              const float* __restrict__ b_o, const float* __restrict__ wc_o,
                              const float* __restrict__ fc_b,
                              short* __restrict__ wfrag, short* __restrict__ fcfrag,
                              float* __restrict__ bias) {
  int tid = blockIdx.x * blockDim.x + threadIdx.x;
  const int total1 = WFRAG_ELEMS;
  const int total2 = FCFRAG_ELEMS;
  for (int e = tid; e < total1 + total2 + HID + OUT_DIM; e += gridDim.x * blockDim.x) {
    if (e < total1) {
      // A-frag of GEMM1: A row (=D row) cidx of tile g, k=32s+8q+j, PERMUTED h
      int j = e & 7, lane = (e >> 3) & 63, s = (e >> 9) & 1, t = e >> 10;
      int q = lane >> 4, cidx = lane & 15;
      int gate = t >> 3;                       // 0:W_i 1:W_c 2:W_o
      int g = t & 7;
      int h = hperm(g, cidx);
      int feat = 32 * s + 8 * q + j;
      const float* W = (gate == 0) ? W_i : ((gate == 1) ? W_c : W_o);
      wfrag[e] = f2bf(W[feat * HID + h]);
    } else if (e < total1 + total2) {
      // A-frag of GEMM2: A = fc_W^T (64x128), STANDARD hid = 32s+8q+j
      int e2 = e - total1;
      int j = e2 & 7, lane = (e2 >> 3) & 63, s = (e2 >> 9) & 3, t = e2 >> 11;
      int q = lane >> 4, cidx = lane & 15;
      int od = 16 * t + cidx;
      int hid = 32 * s + 8 * q + j;
      fcfrag[e2] = f2bf(fc_W[hid * OUT_DIM + od]);
    } else if (e < total1 + total2 + HID) {
      int p = e - total1 - total2;             // permuted storage index g*16+d
      int h = hperm(p >> 4, p & 15);
      bias[p]           = bg_i[h] + b_i[h];
      bias[HID + p]     = bg_c[h] + b_c[h];
      bias[2 * HID + p] = bg_o[h] + b_o[h];
      bias[3 * HID + p] = wc_o[h];
    } else {
      int h2 = e - total1 - total2 - HID;
      bias[4 * HID + h2] = fc_b[h2];
    }
  }
}

// ---- fused main kernel: 8 waves/WG, weights+bias in LDS, no shuffles ----
__global__ __launch_bounds__(512, 6) void gclstm_fused(
    const float* __restrict__ x, const short* __restrict__ wfrag,
    const short* __restrict__ fcfrag, const float* __restrict__ bias,
    float* __restrict__ out) {
  // 49152 B wfrag + 2304 B bias = 51456 B static LDS
  __shared__ __align__(16) char smem[49152 + BIAS_FLOATS * 4];
  short* Wl = (short*)smem;
  float* Bl = (float*)(smem + 49152);

  const int tid = threadIdx.x;
  // ---- stage: wfrag 49152 B = 512 thr x 6 x 16B; bias 2304 B = 144 x 16B
  {
    const uint4_t* src = (const uint4_t*)wfrag;
    uint4_t* dst = (uint4_t*)Wl;
#pragma unroll
    for (int k = 0; k < 6; ++k) dst[k * 512 + tid] = src[k * 512 + tid];
    if (tid < BIAS_FLOATS / 4)
      ((uint4_t*)Bl)[tid] = ((const uint4_t*)bias)[tid];
  }
  __syncthreads();

  const int lane = tid & 63;
  const int wslot = tid >> 6;
  const int wid = blockIdx.x * 8 + wslot;
  const int row0 = wid * 32;
  if (row0 >= N_ROWS) return;            // after barrier: safe
  const int q = lane >> 4, c = lane & 15;
  const short* wfl = Wl + lane * 8;              // LDS, ds_read_b128
  const short* ff  = fcfrag + lane * 8;          // global, L1-resident

  // x B-fragments: B = x^T; lane supplies col (row row0+16m+c), k=32sk+8q+j
  short8 bx[2][2];
#pragma unroll
  for (int m = 0; m < 2; ++m) {
    const float* xr = x + (size_t)(row0 + 16 * m + c) * IN_DIM + 8 * q;
#pragma unroll
    for (int sk = 0; sk < 2; ++sk) {
      f32x4 f0 = *(const f32x4*)(xr + 32 * sk);
      f32x4 f1 = *(const f32x4*)(xr + 32 * sk + 4);
      short8 v;
      v[0] = f2bf(f0[0]); v[1] = f2bf(f0[1]); v[2] = f2bf(f0[2]); v[3] = f2bf(f0[3]);
      v[4] = f2bf(f1[0]); v[5] = f2bf(f1[1]); v[6] = f2bf(f1[2]); v[7] = f2bf(f1[3]);
      bx[m][sk] = v;
    }
  }

  const float* Bi  = Bl;                 // permuted (index g*16+d)
  const float* Bc  = Bl + HID;
  const float* Bo  = Bl + 2 * HID;
  const float* Wco = Bl + 3 * HID;
  const float* Fcb = Bl + 4 * HID;       // standard od order

  // oacc init = fc bias (folded): lane holds out^T[od=16t+4q+r][xrow=16m+c]
  f32x4 oacc[4][2];
#pragma unroll
  for (int t = 0; t < 4; ++t) {
    f32x4 fb = *(const f32x4*)(Fcb + 16 * t + 4 * q);
    oacc[t][0] = fb; oacc[t][1] = fb;
  }

  union U { unsigned u[4]; short8 s8; };

#pragma unroll
  for (int s = 0; s < 4; ++s) {          // 32-hid block = GEMM2 k-step
    unsigned pk[2][2][2];                // [gg][m][word] bf16x2 gate outputs
#pragma unroll
    for (int gg = 0; gg < 2; ++gg) {
      const int g = 2 * s + gg;
      const int p0 = g * 16 + 4 * q;     // permuted bias index base
      f32x4 vbi = *(const f32x4*)(Bi + p0);
      f32x4 vbc = *(const f32x4*)(Bc + p0);
      f32x4 vbo = *(const f32x4*)(Bo + p0);
      f32x4 vwc = *(const f32x4*)(Wco + p0);
      f32x4 acc[3][2];
#pragma unroll
      for (int m = 0; m < 2; ++m) { acc[0][m] = vbi; acc[1][m] = vbc; acc[2][m] = vbo; }
#pragma unroll
      for (int sk = 0; sk < 2; ++sk) {
        short8 ai = *(const short8*)(wfl + ((g     ) * 2 + sk) * 512);
        short8 ac = *(const short8*)(wfl + ((g +  8) * 2 + sk) * 512);
        short8 ao = *(const short8*)(wfl + ((g + 16) * 2 + sk) * 512);
#pragma unroll
        for (int m = 0; m < 2; ++m) {
          acc[0][m] = __builtin_amdgcn_mfma_f32_16x16x32_bf16(ai, bx[m][sk], acc[0][m], 0, 0, 0);
          acc[1][m] = __builtin_amdgcn_mfma_f32_16x16x32_bf16(ac, bx[m][sk], acc[1][m], 0, 0, 0);
          acc[2][m] = __builtin_amdgcn_mfma_f32_16x16x32_bf16(ao, bx[m][sk], acc[2][m], 0, 0, 0);
        }
      }
      // gates -> bf16 pairs. D-row d=4q+r -> hid 32s+2gg+8q+4(r>>1)+(r&1)
#pragma unroll
      for (int m = 0; m < 2; ++m) {
        short hw[4];
#pragma unroll
        for (int r = 0; r < 4; ++r) {
          float gi = fsigmoid(acc[0][m][r]);
          float gt = ftanh(acc[1][m][r]);
          float C  = gi * gt;
          float go = fsigmoid(acc[2][m][r] + vwc[r] * C);
          hw[r] = f2bf(go * ftanh(C));
        }
        pk[gg][m][0] = (unsigned)(unsigned short)hw[0] | ((unsigned)(unsigned short)hw[1] << 16);
        pk[gg][m][1] = (unsigned)(unsigned short)hw[2] | ((unsigned)(unsigned short)hw[3] << 16);
      }
    }
    // GEMM2 B-frag is this lane's own words: {pk0.w0, pk1.w0, pk0.w1, pk1.w1}
#pragma unroll
    for (int m = 0; m < 2; ++m) {
      U bu;
      bu.u[0] = pk[0][m][0];
      bu.u[1] = pk[1][m][0];
      bu.u[2] = pk[0][m][1];
      bu.u[3] = pk[1][m][1];
#pragma unroll
      for (int t = 0; t < 4; ++t) {
        short8 af = *(const short8*)(ff + (t * 4 + s) * 512);
        oacc[t][m] = __builtin_amdgcn_mfma_f32_16x16x32_bf16(af, bu.s8, oacc[t][m], 0, 0, 0);
      }
    }
  }

  // epilogue: float4 stores (fc bias already folded)
#pragma unroll
  for (int t = 0; t < 4; ++t) {
    const int od0 = 16 * t + 4 * q;
#pragma unroll
    for (int m = 0; m < 2; ++m) {
      *(f32x4*)(out + (size_t)(row0 + 16 * m + c) * OUT_DIM + od0) = oacc[t][m];
    }
  }
}

extern "C" void kernel_launch(void* const* d_in, const int* in_sizes, int n_in,
                              void* d_out, int out_size, void* d_ws, size_t ws_size,
                              hipStream_t stream) {
  (void)in_sizes; (void)n_in; (void)out_size; (void)ws_size;
  const float* x    = (const float*)d_in[0];
  const float* W_i  = (const float*)d_in[3];
  const float* W_c  = (const float*)d_in[5];
  const float* W_o  = (const float*)d_in[6];
  const float* bg_i = (const float*)d_in[11];
  const float* bg_c = (const float*)d_in[13];
  const float* bg_o = (const float*)d_in[14];
  const float* wc_o = (const float*)d_in[17];
  const float* b_i  = (const float*)d_in[18];
  const float* b_c  = (const float*)d_in[20];
  const float* b_o  = (const float*)d_in[21];
  const float* fc_W = (const float*)d_in[22];
  const float* fc_b = (const float*)d_in[23];

  short* wfrag  = (short*)d_ws;
  short* fcfrag = (short*)((char*)d_ws + FCFRAG_OFF);
  float* bias   = (float*)((char*)d_ws + BIAS_OFF);

  repack_kernel<<<dim3(64), dim3(256), 0, stream>>>(
      W_i, W_c, W_o, fc_W, bg_i, bg_c, bg_o, b_i, b_c, b_o, wc_o, fc_b,
      wfrag, fcfrag, bias);

  const int nwaves = N_ROWS / 32;           // 6250
  const int nwg = (nwaves + 7) / 8;         // 782 (512-thread WGs, 8 waves)
  gclstm_fused<<<dim3(nwg), dim3(512), 0, stream>>>(
      x, wfrag, fcfrag, bias, (float*)d_out);
}

// Round 6
// 53.820 us; speedup vs baseline: 1.9216x; 1.9216x over previous
//
#include <hip/hip_runtime.h>

// GCLSTM (K=1 Cheb, H0=C0=0) fused kernel for MI355X — v6.
// Math: i=sig(x@Wi+bi'), t=tanh(x@Wc+bc'), C=i*t, o=sig(x@Wo+bo'+wco*C),
//       out = (o*tanh(C)) @ fcW + fcb.  edge_index/batch/Wg_*/W_f unused.
// v6 = v5 with __launch_bounds__(512,4). v5's (512,6) capped VGPR at ~85,
//     the allocator spilled (VGPR_Count=40, +300MB scratch traffic, 103us).
//     Budget 128 VGPR removes the spill; occupancy still LDS-capped at
//     3 WG/CU (24 waves, 75%). Dataflow unchanged from v4: zero-shuffle
//     permuted-h, wfrag(48KB)+bias(2.3KB) in LDS, fcfrag global/L1.

typedef __attribute__((ext_vector_type(8))) short short8;
typedef __attribute__((ext_vector_type(4))) float f32x4;
typedef __attribute__((ext_vector_type(4))) unsigned uint4_t;

#define N_ROWS 200000
#define IN_DIM 64
#define HID 128
#define OUT_DIM 64

// ws layout (bytes)
#define WFRAG_ELEMS (24 * 2 * 64 * 8)   // 24576 bf16 = 49152 B
#define FCFRAG_OFF  49152               // WFRAG_ELEMS*2
#define FCFRAG_ELEMS (4 * 4 * 64 * 8)   // 8192 bf16 = 16384 B
#define BIAS_OFF    65536               // floats: bi[128],bc[128],bo[128],wco[128] (h-permuted), fcb[64]
#define BIAS_FLOATS 576                 // 4*HID + OUT_DIM

__device__ __forceinline__ short f2bf(float f) {
  unsigned u = __float_as_uint(f);
  u += 0x7FFFu + ((u >> 16) & 1u);   // RNE
  return (short)(u >> 16);
}
__device__ __forceinline__ float fexp2(float z) { return __builtin_amdgcn_exp2f(z); }
__device__ __forceinline__ float frcp(float z)  { return __builtin_amdgcn_rcpf(z); }
__device__ __forceinline__ float fsigmoid(float z) {
  return frcp(1.0f + fexp2(-1.44269504f * z));
}
__device__ __forceinline__ float ftanh(float z) {
  return 1.0f - 2.0f * frcp(1.0f + fexp2(2.88539008f * z));
}
// permuted global hid for GEMM1 tile g (0..7), D-row d (0..15)
__device__ __forceinline__ int hperm(int g, int d) {
  return 32 * (g >> 1) + 2 * (g & 1) + 8 * (d >> 2) + 4 * ((d >> 1) & 1) + (d & 1);
}

// ---- repack: weights -> bf16 MFMA A-fragments, biases -> combined fp32 ----
__global__ void repack_kernel(const float* __restrict__ W_i, const float* __restrict__ W_c,
                              const float* __restrict__ W_o, const float* __restrict__ fc_W,
                              const float* __restrict__ bg_i, const float* __restrict__ bg_c,
                              const float* __restrict__ bg_o,
                              const float* __restrict__ b_i, const float* __restrict__ b_c,
                              const float* __restrict__ b_o, const float* __restrict__ wc_o,
                              const float* __restrict__ fc_b,
                              short* __restrict__ wfrag, short* __restrict__ fcfrag,
                              float* __restrict__ bias) {
  int tid = blockIdx.x * blockDim.x + threadIdx.x;
  const int total1 = WFRAG_ELEMS;
  const int total2 = FCFRAG_ELEMS;
  for (int e = tid; e < total1 + total2 + HID + OUT_DIM; e += gridDim.x * blockDim.x) {
    if (e < total1) {
      // A-frag of GEMM1: A row (=D row) cidx of tile g, k=32s+8q+j, PERMUTED h
      int j = e & 7, lane = (e >> 3) & 63, s = (e >> 9) & 1, t = e >> 10;
      int q = lane >> 4, cidx = lane & 15;
      int gate = t >> 3;                       // 0:W_i 1:W_c 2:W_o
      int g = t & 7;
      int h = hperm(g, cidx);
      int feat = 32 * s + 8 * q + j;
      const float* W = (gate == 0) ? W_i : ((gate == 1) ? W_c : W_o);
      wfrag[e] = f2bf(W[feat * HID + h]);
    } else if (e < total1 + total2) {
      // A-frag of GEMM2: A = fc_W^T (64x128), STANDARD hid = 32s+8q+j
      int e2 = e - total1;
      int j = e2 & 7, lane = (e2 >> 3) & 63, s = (e2 >> 9) & 3, t = e2 >> 11;
      int q = lane >> 4, cidx = lane & 15;
      int od = 16 * t + cidx;
      int hid = 32 * s + 8 * q + j;
      fcfrag[e2] = f2bf(fc_W[hid * OUT_DIM + od]);
    } else if (e < total1 + total2 + HID) {
      int p = e - total1 - total2;             // permuted storage index g*16+d
      int h = hperm(p >> 4, p & 15);
      bias[p]           = bg_i[h] + b_i[h];
      bias[HID + p]     = bg_c[h] + b_c[h];
      bias[2 * HID + p] = bg_o[h] + b_o[h];
      bias[3 * HID + p] = wc_o[h];
    } else {
      int h2 = e - total1 - total2 - HID;
      bias[4 * HID + h2] = fc_b[h2];
    }
  }
}

// ---- fused main kernel: 8 waves/WG, weights+bias in LDS, no shuffles ----
__global__ __launch_bounds__(512, 4) void gclstm_fused(
    const float* __restrict__ x, const short* __restrict__ wfrag,
    const short* __restrict__ fcfrag, const float* __restrict__ bias,
    float* __restrict__ out) {
  // 49152 B wfrag + 2304 B bias = 51456 B static LDS
  __shared__ __align__(16) char smem[49152 + BIAS_FLOATS * 4];
  short* Wl = (short*)smem;
  float* Bl = (float*)(smem + 49152);

  const int tid = threadIdx.x;
  // ---- stage: wfrag 49152 B = 512 thr x 6 x 16B; bias 2304 B = 144 x 16B
  {
    const uint4_t* src = (const uint4_t*)wfrag;
    uint4_t* dst = (uint4_t*)Wl;
#pragma unroll
    for (int k = 0; k < 6; ++k) dst[k * 512 + tid] = src[k * 512 + tid];
    if (tid < BIAS_FLOATS / 4)
      ((uint4_t*)Bl)[tid] = ((const uint4_t*)bias)[tid];
  }
  __syncthreads();

  const int lane = tid & 63;
  const int wslot = tid >> 6;
  const int wid = blockIdx.x * 8 + wslot;
  const int row0 = wid * 32;
  if (row0 >= N_ROWS) return;            // after barrier: safe
  const int q = lane >> 4, c = lane & 15;
  const short* wfl = Wl + lane * 8;              // LDS, ds_read_b128
  const short* ff  = fcfrag + lane * 8;          // global, L1-resident

  // x B-fragments: B = x^T; lane supplies col (row row0+16m+c), k=32sk+8q+j
  short8 bx[2][2];
#pragma unroll
  for (int m = 0; m < 2; ++m) {
    const float* xr = x + (size_t)(row0 + 16 * m + c) * IN_DIM + 8 * q;
#pragma unroll
    for (int sk = 0; sk < 2; ++sk) {
      f32x4 f0 = *(const f32x4*)(xr + 32 * sk);
      f32x4 f1 = *(const f32x4*)(xr + 32 * sk + 4);
      short8 v;
      v[0] = f2bf(f0[0]); v[1] = f2bf(f0[1]); v[2] = f2bf(f0[2]); v[3] = f2bf(f0[3]);
      v[4] = f2bf(f1[0]); v[5] = f2bf(f1[1]); v[6] = f2bf(f1[2]); v[7] = f2bf(f1[3]);
      bx[m][sk] = v;
    }
  }

  const float* Bi  = Bl;                 // permuted (index g*16+d)
  const float* Bc  = Bl + HID;
  const float* Bo  = Bl + 2 * HID;
  const float* Wco = Bl + 3 * HID;
  const float* Fcb = Bl + 4 * HID;       // standard od order

  // oacc init = fc bias (folded): lane holds out^T[od=16t+4q+r][xrow=16m+c]
  f32x4 oacc[4][2];
#pragma unroll
  for (int t = 0; t < 4; ++t) {
    f32x4 fb = *(const f32x4*)(Fcb + 16 * t + 4 * q);
    oacc[t][0] = fb; oacc[t][1] = fb;
  }

  union U { unsigned u[4]; short8 s8; };

#pragma unroll
  for (int s = 0; s < 4; ++s) {          // 32-hid block = GEMM2 k-step
    unsigned pk[2][2][2];                // [gg][m][word] bf16x2 gate outputs
#pragma unroll
    for (int gg = 0; gg < 2; ++gg) {
      const int g = 2 * s + gg;
      const int p0 = g * 16 + 4 * q;     // permuted bias index base
      f32x4 vbi = *(const f32x4*)(Bi + p0);
      f32x4 vbc = *(const f32x4*)(Bc + p0);
      f32x4 vbo = *(const f32x4*)(Bo + p0);
      f32x4 vwc = *(const f32x4*)(Wco + p0);
      f32x4 acc[3][2];
#pragma unroll
      for (int m = 0; m < 2; ++m) { acc[0][m] = vbi; acc[1][m] = vbc; acc[2][m] = vbo; }
#pragma unroll
      for (int sk = 0; sk < 2; ++sk) {
        short8 ai = *(const short8*)(wfl + ((g     ) * 2 + sk) * 512);
        short8 ac = *(const short8*)(wfl + ((g +  8) * 2 + sk) * 512);
        short8 ao = *(const short8*)(wfl + ((g + 16) * 2 + sk) * 512);
#pragma unroll
        for (int m = 0; m < 2; ++m) {
          acc[0][m] = __builtin_amdgcn_mfma_f32_16x16x32_bf16(ai, bx[m][sk], acc[0][m], 0, 0, 0);
          acc[1][m] = __builtin_amdgcn_mfma_f32_16x16x32_bf16(ac, bx[m][sk], acc[1][m], 0, 0, 0);
          acc[2][m] = __builtin_amdgcn_mfma_f32_16x16x32_bf16(ao, bx[m][sk], acc[2][m], 0, 0, 0);
        }
      }
      // gates -> bf16 pairs. D-row d=4q+r -> hid 32s+2gg+8q+4(r>>1)+(r&1)
#pragma unroll
      for (int m = 0; m < 2; ++m) {
        short hw[4];
#pragma unroll
        for (int r = 0; r < 4; ++r) {
          float gi = fsigmoid(acc[0][m][r]);
          float gt = ftanh(acc[1][m][r]);
          float C  = gi * gt;
          float go = fsigmoid(acc[2][m][r] + vwc[r] * C);
          hw[r] = f2bf(go * ftanh(C));
        }
        pk[gg][m][0] = (unsigned)(unsigned short)hw[0] | ((unsigned)(unsigned short)hw[1] << 16);
        pk[gg][m][1] = (unsigned)(unsigned short)hw[2] | ((unsigned)(unsigned short)hw[3] << 16);
      }
    }
    // GEMM2 B-frag is this lane's own words: {pk0.w0, pk1.w0, pk0.w1, pk1.w1}
#pragma unroll
    for (int m = 0; m < 2; ++m) {
      U bu;
      bu.u[0] = pk[0][m][0];
      bu.u[1] = pk[1][m][0];
      bu.u[2] = pk[0][m][1];
      bu.u[3] = pk[1][m][1];
#pragma unroll
      for (int t = 0; t < 4; ++t) {
        short8 af = *(const short8*)(ff + (t * 4 + s) * 512);
        oacc[t][m] = __builtin_amdgcn_mfma_f32_16x16x32_bf16(af, bu.s8, oacc[t][m], 0, 0, 0);
      }
    }
  }

  // epilogue: float4 stores (fc bias already folded)
#pragma unroll
  for (int t = 0; t < 4; ++t) {
    const int od0 = 16 * t + 4 * q;
#pragma unroll
    for (int m = 0; m < 2; ++m) {
      *(f32x4*)(out + (size_t)(row0 + 16 * m + c) * OUT_DIM + od0) = oacc[t][m];
    }
  }
}

extern "C" void kernel_launch(void* const* d_in, const int* in_sizes, int n_in,
                              void* d_out, int out_size, void* d_ws, size_t ws_size,
                              hipStream_t stream) {
  (void)in_sizes; (void)n_in; (void)out_size; (void)ws_size;
  const float* x    = (const float*)d_in[0];
  const float* W_i  = (const float*)d_in[3];
  const float* W_c  = (const float*)d_in[5];
  const float* W_o  = (const float*)d_in[6];
  const float* bg_i = (const float*)d_in[11];
  const float* bg_c = (const float*)d_in[13];
  const float* bg_o = (const float*)d_in[14];
  const float* wc_o = (const float*)d_in[17];
  const float* b_i  = (const float*)d_in[18];
  const float* b_c  = (const float*)d_in[20];
  const float* b_o  = (const float*)d_in[21];
  const float* fc_W = (const float*)d_in[22];
  const float* fc_b = (const float*)d_in[23];

  short* wfrag  = (short*)d_ws;
  short* fcfrag = (short*)((char*)d_ws + FCFRAG_OFF);
  float* bias   = (float*)((char*)d_ws + BIAS_OFF);

  repack_kernel<<<dim3(64), dim3(256), 0, stream>>>(
      W_i, W_c, W_o, fc_W, bg_i, bg_c, bg_o, b_i, b_c, b_o, wc_o, fc_b,
      wfrag, fcfrag, bias);

  const int nwaves = N_ROWS / 32;           // 6250
  const int nwg = (nwaves + 7) / 8;         // 782 (512-thread WGs, 8 waves)
  gclstm_fused<<<dim3(nwg), dim3(512), 0, stream>>>(
      x, wfrag, fcfrag, bias, (float*)d_out);
}

// Round 7
// 50.172 us; speedup vs baseline: 2.0612x; 1.0727x over previous
//
#include <hip/hip_runtime.h>

// GCLSTM (K=1 Cheb, H0=C0=0) fused kernel for MI355X — v7.
// Math: i=sig(x@Wi+bi'), t=tanh(x@Wc+bc'), C=i*t, o=sig(x@Wo+bo'+wco*C),
//       out = (o*tanh(C)) @ fcW + fcb.  edge_index/batch/Wg_*/W_f unused.
// v7: two-phase per wave. Phase 1: all 8 GEMM1 h-tiles + gates, H banked in
//     32 u32 registers (independent iterations -> wave-internal pipelining).
//     Phase 2: GEMM2 as a dense 16-load + 32-MFMA block (af off critical
//     path, L1-hot). All f32->bf16 via v_cvt_pk_bf16_f32 (1 instr / pair,
//     was ~6 int ops/elem). Zero-shuffle permuted-h dataflow from v4;
//     wfrag+bias staged in LDS per 512-thread WG.

typedef __attribute__((ext_vector_type(8))) short short8;
typedef __attribute__((ext_vector_type(4))) float f32x4;
typedef __attribute__((ext_vector_type(4))) unsigned uint4_t;

#define N_ROWS 200000
#define IN_DIM 64
#define HID 128
#define OUT_DIM 64

// ws layout (bytes)
#define WFRAG_ELEMS (24 * 2 * 64 * 8)   // 24576 bf16 = 49152 B
#define FCFRAG_OFF  49152               // WFRAG_ELEMS*2
#define FCFRAG_ELEMS (4 * 4 * 64 * 8)   // 8192 bf16 = 16384 B
#define BIAS_OFF    65536               // floats: bi[128],bc[128],bo[128],wco[128] (h-permuted), fcb[64]
#define BIAS_FLOATS 576                 // 4*HID + OUT_DIM

__device__ __forceinline__ short f2bf(float f) {
  unsigned u = __float_as_uint(f);
  u += 0x7FFFu + ((u >> 16) & 1u);   // RNE (repack only)
  return (short)(u >> 16);
}
__device__ __forceinline__ unsigned cvt_pk_bf16(float lo, float hi) {
  unsigned r;
  asm("v_cvt_pk_bf16_f32 %0, %1, %2" : "=v"(r) : "v"(lo), "v"(hi));
  return r;
}
__device__ __forceinline__ float fexp2(float z) { return __builtin_amdgcn_exp2f(z); }
__device__ __forceinline__ float frcp(float z)  { return __builtin_amdgcn_rcpf(z); }
__device__ __forceinline__ float fsigmoid(float z) {
  return frcp(1.0f + fexp2(-1.44269504f * z));
}
__device__ __forceinline__ float ftanh(float z) {
  return 1.0f - 2.0f * frcp(1.0f + fexp2(2.88539008f * z));
}
// permuted global hid for GEMM1 tile g (0..7), D-row d (0..15)
__device__ __forceinline__ int hperm(int g, int d) {
  return 32 * (g >> 1) + 2 * (g & 1) + 8 * (d >> 2) + 4 * ((d >> 1) & 1) + (d & 1);
}

// ---- repack: weights -> bf16 MFMA A-fragments, biases -> combined fp32 ----
__global__ void repack_kernel(const float* __restrict__ W_i, const float* __restrict__ W_c,
                              const float* __restrict__ W_o, const float* __restrict__ fc_W,
                              const float* __restrict__ bg_i, const float* __restrict__ bg_c,
                              const float* __restrict__ bg_o,
                              const float* __restrict__ b_i, const float* __restrict__ b_c,
                              const float* __restrict__ b_o, const float* __restrict__ wc_o,
                              const float* __restrict__ fc_b,
                              short* __restrict__ wfrag, short* __restrict__ fcfrag,
                              float* __restrict__ bias) {
  int tid = blockIdx.x * blockDim.x + threadIdx.x;
  const int total1 = WFRAG_ELEMS;
  const int total2 = FCFRAG_ELEMS;
  for (int e = tid; e < total1 + total2 + HID + OUT_DIM; e += gridDim.x * blockDim.x) {
    if (e < total1) {
      // A-frag of GEMM1: A row (=D row) cidx of tile g, k=32s+8q+j, PERMUTED h
      int j = e & 7, lane = (e >> 3) & 63, s = (e >> 9) & 1, t = e >> 10;
      int q = lane >> 4, cidx = lane & 15;
      int gate = t >> 3;                       // 0:W_i 1:W_c 2:W_o
      int g = t & 7;
      int h = hperm(g, cidx);
      int feat = 32 * s + 8 * q + j;
      const float* W = (gate == 0) ? W_i : ((gate == 1) ? W_c : W_o);
      wfrag[e] = f2bf(W[feat * HID + h]);
    } else if (e < total1 + total2) {
      // A-frag of GEMM2: A = fc_W^T (64x128), STANDARD hid = 32s+8q+j
      int e2 = e - total1;
      int j = e2 & 7, lane = (e2 >> 3) & 63, s = (e2 >> 9) & 3, t = e2 >> 11;
      int q = lane >> 4, cidx = lane & 15;
      int od = 16 * t + cidx;
      int hid = 32 * s + 8 * q + j;
      fcfrag[e2] = f2bf(fc_W[hid * OUT_DIM + od]);
    } else if (e < total1 + total2 + HID) {
      int p = e - total1 - total2;             // permuted storage index g*16+d
      int h = hperm(p >> 4, p & 15);
      bias[p]           = bg_i[h] + b_i[h];
      bias[HID + p]     = bg_c[h] + b_c[h];
      bias[2 * HID + p] = bg_o[h] + b_o[h];
      bias[3 * HID + p] = wc_o[h];
    } else {
      int h2 = e - total1 - total2 - HID;
      bias[4 * HID + h2] = fc_b[h2];
    }
  }
}

// ---- fused main kernel: 8 waves/WG, two-phase, H in registers ----
__global__ __launch_bounds__(512, 4) void gclstm_fused(
    const float* __restrict__ x, const short* __restrict__ wfrag,
    const short* __restrict__ fcfrag, const float* __restrict__ bias,
    float* __restrict__ out) {
  // 49152 B wfrag + 2304 B bias = 51456 B static LDS
  __shared__ __align__(16) char smem[49152 + BIAS_FLOATS * 4];
  short* Wl = (short*)smem;
  float* Bl = (float*)(smem + 49152);

  const int tid = threadIdx.x;
  // ---- stage: wfrag 49152 B = 512 thr x 6 x 16B; bias 2304 B = 144 x 16B
  {
    const uint4_t* src = (const uint4_t*)wfrag;
    uint4_t* dst = (uint4_t*)Wl;
#pragma unroll
    for (int k = 0; k < 6; ++k) dst[k * 512 + tid] = src[k * 512 + tid];
    if (tid < BIAS_FLOATS / 4)
      ((uint4_t*)Bl)[tid] = ((const uint4_t*)bias)[tid];
  }
  __syncthreads();

  const int lane = tid & 63;
  const int wslot = tid >> 6;
  const int wid = blockIdx.x * 8 + wslot;
  const int row0 = wid * 32;
  if (row0 >= N_ROWS) return;            // after barrier: safe
  const int q = lane >> 4, c = lane & 15;
  const short* wfl = Wl + lane * 8;              // LDS, ds_read_b128
  const short* ff  = fcfrag + lane * 8;          // global, L1-resident (16KB)

  // x B-fragments: B = x^T; lane supplies col (row row0+16m+c), k=32sk+8q+j
  short8 bx[2][2];
  union U { unsigned u[4]; short8 s8; };
#pragma unroll
  for (int m = 0; m < 2; ++m) {
    const float* xr = x + (size_t)(row0 + 16 * m + c) * IN_DIM + 8 * q;
#pragma unroll
    for (int sk = 0; sk < 2; ++sk) {
      f32x4 f0 = *(const f32x4*)(xr + 32 * sk);
      f32x4 f1 = *(const f32x4*)(xr + 32 * sk + 4);
      U v;
      v.u[0] = cvt_pk_bf16(f0[0], f0[1]);
      v.u[1] = cvt_pk_bf16(f0[2], f0[3]);
      v.u[2] = cvt_pk_bf16(f1[0], f1[1]);
      v.u[3] = cvt_pk_bf16(f1[2], f1[3]);
      bx[m][sk] = v.s8;
    }
  }

  const float* Bi  = Bl;                 // permuted (index g*16+d)
  const float* Bc  = Bl + HID;
  const float* Bo  = Bl + 2 * HID;
  const float* Wco = Bl + 3 * HID;
  const float* Fcb = Bl + 4 * HID;       // standard od order

  // ---- Phase 1: all 8 GEMM1 h-tiles + gates; H banked in 32 u32 regs ----
  unsigned hbuf[8][2][2];                // [g][m][word], g = 2s+gg
#pragma unroll
  for (int g = 0; g < 8; ++g) {
    const int p0 = g * 16 + 4 * q;       // permuted bias index base
    f32x4 vbi = *(const f32x4*)(Bi + p0);
    f32x4 vbc = *(const f32x4*)(Bc + p0);
    f32x4 vbo = *(const f32x4*)(Bo + p0);
    f32x4 vwc = *(const f32x4*)(Wco + p0);
    f32x4 acc[3][2];
#pragma unroll
    for (int m = 0; m < 2; ++m) { acc[0][m] = vbi; acc[1][m] = vbc; acc[2][m] = vbo; }
#pragma unroll
    for (int sk = 0; sk < 2; ++sk) {
      short8 ai = *(const short8*)(wfl + ((g     ) * 2 + sk) * 512);
      short8 ac = *(const short8*)(wfl + ((g +  8) * 2 + sk) * 512);
      short8 ao = *(const short8*)(wfl + ((g + 16) * 2 + sk) * 512);
#pragma unroll
      for (int m = 0; m < 2; ++m) {
        acc[0][m] = __builtin_amdgcn_mfma_f32_16x16x32_bf16(ai, bx[m][sk], acc[0][m], 0, 0, 0);
        acc[1][m] = __builtin_amdgcn_mfma_f32_16x16x32_bf16(ac, bx[m][sk], acc[1][m], 0, 0, 0);
        acc[2][m] = __builtin_amdgcn_mfma_f32_16x16x32_bf16(ao, bx[m][sk], acc[2][m], 0, 0, 0);
      }
    }
    // gates -> packed bf16 pairs (cvt_pk). D-row d=4q+r -> hid 32s+2gg+8q+4(r>>1)+(r&1)
#pragma unroll
    for (int m = 0; m < 2; ++m) {
      float hw[4];
#pragma unroll
      for (int r = 0; r < 4; ++r) {
        float gi = fsigmoid(acc[0][m][r]);
        float gt = ftanh(acc[1][m][r]);
        float C  = gi * gt;
        float go = fsigmoid(acc[2][m][r] + vwc[r] * C);
        hw[r] = go * ftanh(C);
      }
      hbuf[g][m][0] = cvt_pk_bf16(hw[0], hw[1]);
      hbuf[g][m][1] = cvt_pk_bf16(hw[2], hw[3]);
    }
  }

  // ---- Phase 2: GEMM2 dense block. oacc init = fc bias (folded) ----
  f32x4 oacc[4][2];
#pragma unroll
  for (int t = 0; t < 4; ++t) {
    f32x4 fb = *(const f32x4*)(Fcb + 16 * t + 4 * q);
    oacc[t][0] = fb; oacc[t][1] = fb;
  }
#pragma unroll
  for (int s = 0; s < 4; ++s) {
#pragma unroll
    for (int m = 0; m < 2; ++m) {
      U bu;
      bu.u[0] = hbuf[2 * s][m][0];
      bu.u[1] = hbuf[2 * s + 1][m][0];
      bu.u[2] = hbuf[2 * s][m][1];
      bu.u[3] = hbuf[2 * s + 1][m][1];
#pragma unroll
      for (int t = 0; t < 4; ++t) {
        short8 af = *(const short8*)(ff + (t * 4 + s) * 512);
        oacc[t][m] = __builtin_amdgcn_mfma_f32_16x16x32_bf16(af, bu.s8, oacc[t][m], 0, 0, 0);
      }
    }
  }

  // epilogue: coalesced float4 stores (fc bias already folded)
#pragma unroll
  for (int t = 0; t < 4; ++t) {
    const int od0 = 16 * t + 4 * q;
#pragma unroll
    for (int m = 0; m < 2; ++m) {
      *(f32x4*)(out + (size_t)(row0 + 16 * m + c) * OUT_DIM + od0) = oacc[t][m];
    }
  }
}

extern "C" void kernel_launch(void* const* d_in, const int* in_sizes, int n_in,
                              void* d_out, int out_size, void* d_ws, size_t ws_size,
                              hipStream_t stream) {
  (void)in_sizes; (void)n_in; (void)out_size; (void)ws_size;
  const float* x    = (const float*)d_in[0];
  const float* W_i  = (const float*)d_in[3];
  const float* W_c  = (const float*)d_in[5];
  const float* W_o  = (const float*)d_in[6];
  const float* bg_i = (const float*)d_in[11];
  const float* bg_c = (const float*)d_in[13];
  const float* bg_o = (const float*)d_in[14];
  const float* wc_o = (const float*)d_in[17];
  const float* b_i  = (const float*)d_in[18];
  const float* b_c  = (const float*)d_in[20];
  const float* b_o  = (const float*)d_in[21];
  const float* fc_W = (const float*)d_in[22];
  const float* fc_b = (const float*)d_in[23];

  short* wfrag  = (short*)d_ws;
  short* fcfrag = (short*)((char*)d_ws + FCFRAG_OFF);
  float* bias   = (float*)((char*)d_ws + BIAS_OFF);

  repack_kernel<<<dim3(64), dim3(256), 0, stream>>>(
      W_i, W_c, W_o, fc_W, bg_i, bg_c, bg_o, b_i, b_c, b_o, wc_o, fc_b,
      wfrag, fcfrag, bias);

  const int nwaves = N_ROWS / 32;           // 6250
  const int nwg = (nwaves + 7) / 8;         // 782 (512-thread WGs, 8 waves)
  gclstm_fused<<<dim3(nwg), dim3(512), 0, stream>>>(
      x, wfrag, fcfrag, bias, (float*)d_out);
}